// Round 1
// baseline (1601.209 us; speedup 1.0000x reference)
//
#include <hip/hip_runtime.h>

#define N_NODES 10000
#define N_EDGES 100000
#define D 248
#define H 512
#define NNZ 2480
#define LN_EPS 1e-5f

// ---------------------------------------------------------------------------
// Tiled fp32 GEMM, C = A @ B^T (+bias)(+silu).
// A: (M,K) row-major. B: (N,K) row-major (torch Linear weight layout).
// ACT: 0 = none, 1 = +bias +silu, 2 = +bias
// BM=BN=64, BK=8, 256 threads, 4x4 register blocking.
// ---------------------------------------------------------------------------
template <int ACT>
__global__ __launch_bounds__(256) void gemm_nt(
    const float* __restrict__ A, const float* __restrict__ B,
    const float* __restrict__ bias, float* __restrict__ Cout,
    int M, int Nn, int K) {
  constexpr int BM = 64, BN = 64, BK = 8;
  __shared__ float As[BK][BM];
  __shared__ float Bs[BK][BN];
  const int tid = threadIdx.x;
  const int tx = tid & 15;        // 0..15 -> output col group
  const int ty = tid >> 4;        // 0..15 -> output row group
  const int m0 = blockIdx.y * BM;
  const int n0 = blockIdx.x * BN;

  float acc[4][4] = {};

  for (int k0 = 0; k0 < K; k0 += BK) {
#pragma unroll
    for (int i = 0; i < 2; i++) {
      int idx = tid + i * 256;          // 0..511
      int r = idx >> 3;                 // 0..63
      int c = idx & 7;                  // 0..7
      int gm = m0 + r;
      As[c][r] = (gm < M) ? A[(long)gm * K + k0 + c] : 0.f;
      int gn = n0 + r;
      Bs[c][r] = (gn < Nn) ? B[(long)gn * K + k0 + c] : 0.f;
    }
    __syncthreads();
#pragma unroll
    for (int k = 0; k < BK; k++) {
      float a[4], b[4];
#pragma unroll
      for (int i = 0; i < 4; i++) a[i] = As[k][ty * 4 + i];
#pragma unroll
      for (int j = 0; j < 4; j++) b[j] = Bs[k][tx * 4 + j];
#pragma unroll
      for (int i = 0; i < 4; i++)
#pragma unroll
        for (int j = 0; j < 4; j++) acc[i][j] += a[i] * b[j];
    }
    __syncthreads();
  }

#pragma unroll
  for (int i = 0; i < 4; i++) {
    int gm = m0 + ty * 4 + i;
    if (gm >= M) continue;
#pragma unroll
    for (int j = 0; j < 4; j++) {
      int gn = n0 + tx * 4 + j;
      if (gn >= Nn) continue;
      float v = acc[i][j];
      if (ACT >= 1) v += bias[gn];
      if (ACT == 1) v = v / (1.f + __expf(-v));  // silu
      Cout[(long)gm * Nn + gn] = v;
    }
  }
}

// ---------------------------------------------------------------------------
// Zero-init (ws is poisoned 0xAA before every timed launch)
// ---------------------------------------------------------------------------
__global__ void zero_kernel(float* __restrict__ p, int n) {
  int i = blockIdx.x * blockDim.x + threadIdx.x;
  if (i < n) p[i] = 0.f;
}

// ---------------------------------------------------------------------------
// Per-edge sparse Lie bracket + scatter-add onto targets.
// One wave (64 lanes) per edge; 4 edges per 256-thread block.
// Stages P[src] and F[tgt] rows in LDS, accumulates msg[K] with LDS atomics,
// then scatter-adds into agg[tgt] with global f32 atomics.
// ---------------------------------------------------------------------------
__global__ __launch_bounds__(256) void edge_kernel(
    const float* __restrict__ P, const float* __restrict__ F,
    const int* __restrict__ ei, const int* __restrict__ Iv,
    const int* __restrict__ Jv, const int* __restrict__ Kv,
    const float* __restrict__ Cv, float* __restrict__ agg) {
  __shared__ float sP[4][D];
  __shared__ float sF[4][D];
  __shared__ float sM[4][D];
  const int w = threadIdx.x >> 6;
  const int lane = threadIdx.x & 63;
  const int e = blockIdx.x * 4 + w;
  const bool valid = (e < N_EDGES);
  int src = 0, tgt = 0;
  if (valid) {
    src = ei[e];
    tgt = ei[N_EDGES + e];
    for (int j = lane; j < D; j += 64) {
      sP[w][j] = P[(long)src * D + j];
      sF[w][j] = F[(long)tgt * D + j];
      sM[w][j] = 0.f;
    }
  }
  __syncthreads();
  if (valid) {
    for (int t = lane; t < NNZ; t += 64) {
      float prod = Cv[t] * sP[w][Iv[t]] * sF[w][Jv[t]];
      atomicAdd(&sM[w][Kv[t]], prod);  // LDS atomic (ds_add_f32)
    }
  }
  __syncthreads();
  if (valid) {
    for (int j = lane; j < D; j += 64) {
      unsafeAtomicAdd(&agg[(long)tgt * D + j], sM[w][j]);  // native global f32 atomic
    }
  }
}

// ---------------------------------------------------------------------------
// Residual + LayerNorm: out = LN(features + h2) * gamma + beta, one block/row
// ---------------------------------------------------------------------------
__global__ __launch_bounds__(256) void ln_kernel(
    const float* __restrict__ x0, const float* __restrict__ h2,
    const float* __restrict__ gamma, const float* __restrict__ beta,
    float* __restrict__ out) {
  const int n = blockIdx.x;
  const int tid = threadIdx.x;
  __shared__ float red[256];
  float x = 0.f;
  if (tid < D) x = x0[(long)n * D + tid] + h2[(long)n * D + tid];
  red[tid] = (tid < D) ? x : 0.f;
  __syncthreads();
  for (int s = 128; s > 0; s >>= 1) {
    if (tid < s) red[tid] += red[tid + s];
    __syncthreads();
  }
  const float mu = red[0] / (float)D;
  __syncthreads();
  const float xc = (tid < D) ? (x - mu) : 0.f;
  red[tid] = xc * xc;
  __syncthreads();
  for (int s = 128; s > 0; s >>= 1) {
    if (tid < s) red[tid] += red[tid + s];
    __syncthreads();
  }
  const float var = red[0] / (float)D;
  const float rstd = rsqrtf(var + LN_EPS);
  if (tid < D) out[(long)n * D + tid] = xc * rstd * gamma[tid] + beta[tid];
}

// ---------------------------------------------------------------------------
extern "C" void kernel_launch(void* const* d_in, const int* in_sizes, int n_in,
                              void* d_out, int out_size, void* d_ws, size_t ws_size,
                              hipStream_t stream) {
  const float* features = (const float*)d_in[0];
  const int*   ei       = (const int*)d_in[1];   // (2, E)
  const float* W_msg    = (const float*)d_in[2]; // (D, D)
  const float* W1       = (const float*)d_in[3]; // (H, D)
  const float* b1       = (const float*)d_in[4]; // (H,)
  const float* W2       = (const float*)d_in[5]; // (D, H)
  const float* b2       = (const float*)d_in[6]; // (D,)
  const float* gamma    = (const float*)d_in[7]; // (D,)
  const float* beta     = (const float*)d_in[8]; // (D,)
  const int*   Iv       = (const int*)d_in[9];
  const int*   Jv       = (const int*)d_in[10];
  const int*   Kv       = (const int*)d_in[11];
  const float* Cv       = (const float*)d_in[12];
  float* out = (float*)d_out;

  char* ws = (char*)d_ws;
  const size_t ND = (size_t)N_NODES * D * sizeof(float);  // 9.92 MB
  const size_t NH = (size_t)N_NODES * H * sizeof(float);  // 20.48 MB
  float* P   = (float*)(ws);                // projected node features (N,D)
  float* agg = (float*)(ws + ND);           // aggregated messages (N,D)
  float* H1  = (float*)(ws + 2 * ND);       // hidden (N,H)
  float* H2  = (float*)(ws + 2 * ND + NH);  // mlp out (N,D)

  dim3 blk(256);

  // 1) P = features @ W_msg^T   (node-level projection instead of edge-level)
  {
    dim3 g((D + 63) / 64, (N_NODES + 63) / 64);
    gemm_nt<0><<<g, blk, 0, stream>>>(features, W_msg, nullptr, P, N_NODES, D, D);
  }
  // 2) agg = 0
  zero_kernel<<<(N_NODES * D + 255) / 256, blk, 0, stream>>>(agg, N_NODES * D);
  // 3) per-edge bracket + scatter
  edge_kernel<<<(N_EDGES + 3) / 4, blk, 0, stream>>>(P, features, ei, Iv, Jv, Kv, Cv, agg);
  // 4) H1 = silu(agg @ W1^T + b1)
  {
    dim3 g((H + 63) / 64, (N_NODES + 63) / 64);
    gemm_nt<1><<<g, blk, 0, stream>>>(agg, W1, b1, H1, N_NODES, H, D);
  }
  // 5) H2 = H1 @ W2^T + b2
  {
    dim3 g((D + 63) / 64, (N_NODES + 63) / 64);
    gemm_nt<2><<<g, blk, 0, stream>>>(H1, W2, b2, H2, N_NODES, D, H);
  }
  // 6) out = LN(features + H2)
  ln_kernel<<<N_NODES, blk, 0, stream>>>(features, H2, gamma, beta, out);
}

// Round 2
// 711.664 us; speedup vs baseline: 2.2500x; 2.2500x over previous
//
#include <hip/hip_runtime.h>

#define N_NODES 10000
#define N_EDGES 100000
#define D 248
#define H 512
#define NNZ 2480
#define LN_EPS 1e-5f

// ---------------------------------------------------------------------------
// Tiled fp32 GEMM, C = A @ B^T (+bias)(+silu).
// A: (M,K) row-major. B: (N,K) row-major (torch Linear weight layout).
// ACT: 0 = none, 1 = +bias +silu, 2 = +bias
// ---------------------------------------------------------------------------
template <int ACT>
__global__ __launch_bounds__(256) void gemm_nt(
    const float* __restrict__ A, const float* __restrict__ B,
    const float* __restrict__ bias, float* __restrict__ Cout,
    int M, int Nn, int K) {
  constexpr int BM = 64, BN = 64, BK = 8;
  __shared__ float As[BK][BM];
  __shared__ float Bs[BK][BN];
  const int tid = threadIdx.x;
  const int tx = tid & 15;
  const int ty = tid >> 4;
  const int m0 = blockIdx.y * BM;
  const int n0 = blockIdx.x * BN;

  float acc[4][4] = {};

  for (int k0 = 0; k0 < K; k0 += BK) {
#pragma unroll
    for (int i = 0; i < 2; i++) {
      int idx = tid + i * 256;
      int r = idx >> 3;
      int c = idx & 7;
      int gm = m0 + r;
      As[c][r] = (gm < M) ? A[(long)gm * K + k0 + c] : 0.f;
      int gn = n0 + r;
      Bs[c][r] = (gn < Nn) ? B[(long)gn * K + k0 + c] : 0.f;
    }
    __syncthreads();
#pragma unroll
    for (int k = 0; k < BK; k++) {
      float a[4], b[4];
#pragma unroll
      for (int i = 0; i < 4; i++) a[i] = As[k][ty * 4 + i];
#pragma unroll
      for (int j = 0; j < 4; j++) b[j] = Bs[k][tx * 4 + j];
#pragma unroll
      for (int i = 0; i < 4; i++)
#pragma unroll
        for (int j = 0; j < 4; j++) acc[i][j] += a[i] * b[j];
    }
    __syncthreads();
  }

#pragma unroll
  for (int i = 0; i < 4; i++) {
    int gm = m0 + ty * 4 + i;
    if (gm >= M) continue;
#pragma unroll
    for (int j = 0; j < 4; j++) {
      int gn = n0 + tx * 4 + j;
      if (gn >= Nn) continue;
      float v = acc[i][j];
      if (ACT >= 1) v += bias[gn];
      if (ACT == 1) v = v / (1.f + __expf(-v));  // silu
      Cout[(long)gm * Nn + gn] = v;
    }
  }
}

// ---------------------------------------------------------------------------
// Zero-init via float4 (ws is poisoned 0xAA before every timed launch)
// ---------------------------------------------------------------------------
__global__ void zero4_kernel(float4* __restrict__ p, int n4) {
  int i = blockIdx.x * blockDim.x + threadIdx.x;
  if (i < n4) p[i] = make_float4(0.f, 0.f, 0.f, 0.f);
}

// ---------------------------------------------------------------------------
// Build CSR of structure-constant triples sorted by output index K.
// Single block; NNZ=2480 is tiny (~µs). Runs every launch (no static state).
// ---------------------------------------------------------------------------
__global__ __launch_bounds__(256) void build_csr(
    const int* __restrict__ Iv, const int* __restrict__ Jv,
    const int* __restrict__ Kv, const float* __restrict__ Cv,
    int* __restrict__ row_start, int* __restrict__ tI,
    int* __restrict__ tJ, float* __restrict__ tC) {
  __shared__ int cnt[D];
  __shared__ int off[D];
  const int tid = threadIdx.x;
  for (int k = tid; k < D; k += 256) cnt[k] = 0;
  __syncthreads();
  for (int t = tid; t < NNZ; t += 256) atomicAdd(&cnt[Kv[t]], 1);
  __syncthreads();
  if (tid == 0) {
    int run = 0;
    for (int k = 0; k < D; k++) {
      off[k] = run;
      row_start[k] = run;
      run += cnt[k];
    }
    row_start[D] = run;  // == NNZ
  }
  __syncthreads();
  for (int t = tid; t < NNZ; t += 256) {
    int pos = atomicAdd(&off[Kv[t]], 1);
    tI[pos] = Iv[t];
    tJ[pos] = Jv[t];
    tC[pos] = Cv[t];
  }
}

// ---------------------------------------------------------------------------
// Edge scatter: S[tgt] += P[src], one wave per edge, float4 reads, f32 atomics
// ---------------------------------------------------------------------------
__global__ __launch_bounds__(256) void scatter_kernel(
    const float* __restrict__ P, const int* __restrict__ ei,
    float* __restrict__ S) {
  const int gid = blockIdx.x * 256 + threadIdx.x;
  const int e = gid >> 6;
  const int lane = gid & 63;
  if (e >= N_EDGES || lane >= 62) return;
  const int src = ei[e];
  const int tgt = ei[N_EDGES + e];
  float4 v = ((const float4*)(P + (long)src * D))[lane];
  float* dst = S + (long)tgt * D + lane * 4;
  unsafeAtomicAdd(dst + 0, v.x);
  unsafeAtomicAdd(dst + 1, v.y);
  unsafeAtomicAdd(dst + 2, v.z);
  unsafeAtomicAdd(dst + 3, v.w);
}

// ---------------------------------------------------------------------------
// Per-NODE bracket: agg[n][k] = sum_{t in CSR row k} C_t * S[n][I_t] * F[n][J_t]
// Block per node; thread k owns output k -> no atomics at all.
// Triples arrays are 30 KB -> L1-resident across the 10000 blocks.
// ---------------------------------------------------------------------------
__global__ __launch_bounds__(256) void bracket_kernel(
    const float* __restrict__ S, const float* __restrict__ F,
    const int* __restrict__ row_start, const int* __restrict__ tI,
    const int* __restrict__ tJ, const float* __restrict__ tC,
    float* __restrict__ agg) {
  const int n = blockIdx.x;
  __shared__ __align__(16) float sS[D];
  __shared__ __align__(16) float sF[D];
  const int tid = threadIdx.x;
  if (tid < 62) {
    ((float4*)sS)[tid] = ((const float4*)(S + (long)n * D))[tid];
    ((float4*)sF)[tid] = ((const float4*)(F + (long)n * D))[tid];
  }
  __syncthreads();
  if (tid < D) {
    float acc = 0.f;
    const int beg = row_start[tid], end = row_start[tid + 1];
    for (int t = beg; t < end; t++)
      acc += tC[t] * sS[tI[t]] * sF[tJ[t]];
    agg[(long)n * D + tid] = acc;
  }
}

// ---------------------------------------------------------------------------
// Residual + LayerNorm: out = LN(features + h2) * gamma + beta, one block/row
// ---------------------------------------------------------------------------
__global__ __launch_bounds__(256) void ln_kernel(
    const float* __restrict__ x0, const float* __restrict__ h2,
    const float* __restrict__ gamma, const float* __restrict__ beta,
    float* __restrict__ out) {
  const int n = blockIdx.x;
  const int tid = threadIdx.x;
  __shared__ float red[256];
  float x = 0.f;
  if (tid < D) x = x0[(long)n * D + tid] + h2[(long)n * D + tid];
  red[tid] = (tid < D) ? x : 0.f;
  __syncthreads();
  for (int s = 128; s > 0; s >>= 1) {
    if (tid < s) red[tid] += red[tid + s];
    __syncthreads();
  }
  const float mu = red[0] / (float)D;
  __syncthreads();
  const float xc = (tid < D) ? (x - mu) : 0.f;
  red[tid] = xc * xc;
  __syncthreads();
  for (int s = 128; s > 0; s >>= 1) {
    if (tid < s) red[tid] += red[tid + s];
    __syncthreads();
  }
  const float var = red[0] / (float)D;
  const float rstd = rsqrtf(var + LN_EPS);
  if (tid < D) out[(long)n * D + tid] = xc * rstd * gamma[tid] + beta[tid];
}

// ---------------------------------------------------------------------------
extern "C" void kernel_launch(void* const* d_in, const int* in_sizes, int n_in,
                              void* d_out, int out_size, void* d_ws, size_t ws_size,
                              hipStream_t stream) {
  const float* features = (const float*)d_in[0];
  const int*   ei       = (const int*)d_in[1];   // (2, E)
  const float* W_msg    = (const float*)d_in[2]; // (D, D)
  const float* W1       = (const float*)d_in[3]; // (H, D)
  const float* b1       = (const float*)d_in[4]; // (H,)
  const float* W2       = (const float*)d_in[5]; // (D, H)
  const float* b2       = (const float*)d_in[6]; // (D,)
  const float* gamma    = (const float*)d_in[7]; // (D,)
  const float* beta     = (const float*)d_in[8]; // (D,)
  const int*   Iv       = (const int*)d_in[9];
  const int*   Jv       = (const int*)d_in[10];
  const int*   Kv       = (const int*)d_in[11];
  const float* Cv       = (const float*)d_in[12];
  float* out = (float*)d_out;

  char* ws = (char*)d_ws;
  const size_t ND = (size_t)N_NODES * D * sizeof(float);  // 9.92 MB
  const size_t NH = (size_t)N_NODES * H * sizeof(float);  // 20.48 MB
  float* P   = (float*)(ws);                 // projected nodes (N,D)
  float* S   = (float*)(ws + ND);            // scatter-summed P (N,D)
  float* H1  = (float*)(ws + 2 * ND);        // hidden (N,H)
  float* agg = P;                            // alias: P dead after scatter
  float* H2  = S;                            // alias: S dead after bracket... (see order)
  char*  csr = ws + 2 * ND + NH;
  int*   row_start = (int*)csr;              // D+1 ints (pad to 256)
  int*   tI = (int*)(csr + 1024);
  int*   tJ = tI + NNZ;
  float* tC = (float*)(tJ + NNZ);

  dim3 blk(256);

  // 1) P = features @ W_msg^T   (project NODES, not edges: 10x fewer FLOPs)
  {
    dim3 g((D + 63) / 64, (N_NODES + 63) / 64);
    gemm_nt<0><<<g, blk, 0, stream>>>(features, W_msg, nullptr, P, N_NODES, D, D);
  }
  // 2) S = 0
  zero4_kernel<<<(N_NODES * D / 4 + 255) / 256, blk, 0, stream>>>((float4*)S, N_NODES * D / 4);
  // 3) CSR of triples by K (single tiny block)
  build_csr<<<1, blk, 0, stream>>>(Iv, Jv, Kv, Cv, row_start, tI, tJ, tC);
  // 4) S[tgt] += P[src]  (dense row scatter, the only atomics left)
  scatter_kernel<<<(N_EDGES * 64) / 256, blk, 0, stream>>>(P, ei, S);
  // 5) agg[n][k] = sum_t C_t * S[n][I_t] * F[n][J_t]   (per-node, atomic-free)
  bracket_kernel<<<N_NODES, blk, 0, stream>>>(S, features, row_start, tI, tJ, tC, agg);
  // 6) H1 = silu(agg @ W1^T + b1)
  {
    dim3 g((H + 63) / 64, (N_NODES + 63) / 64);
    gemm_nt<1><<<g, blk, 0, stream>>>(agg, W1, b1, H1, N_NODES, H, D);
  }
  // 7) H2 = H1 @ W2^T + b2   (H2 aliases S, dead after step 5)
  {
    dim3 g((D + 63) / 64, (N_NODES + 63) / 64);
    gemm_nt<2><<<g, blk, 0, stream>>>(H1, W2, b2, H2, N_NODES, D, H);
  }
  // 8) out = LN(features + H2)
  ln_kernel<<<N_NODES, blk, 0, stream>>>(features, H2, gamma, beta, out);
}

// Round 3
// 297.984 us; speedup vs baseline: 5.3735x; 2.3883x over previous
//
#include <hip/hip_runtime.h>
#include <hip/hip_bf16.h>

#define N_NODES 10000
#define N_EDGES 100000
#define D 248
#define DP 256      // padded D (K/N padding for MFMA tiles)
#define HDIM 512
#define NNZ 2480
#define LN_EPS 1e-5f

typedef __attribute__((ext_vector_type(8))) short bf16x8_t;  // 8 bf16 = 4 VGPRs
typedef __attribute__((ext_vector_type(4))) float f32x4_t;   // MFMA accum

__device__ __forceinline__ float bf2f(unsigned short u) {
  unsigned int x = ((unsigned int)u) << 16;
  return __builtin_bit_cast(float, x);
}

// ---------------------------------------------------------------------------
// Cast fp32 (sr, sc) -> bf16 (gridDim.x rows, dc cols), zero-padding OOB.
// ---------------------------------------------------------------------------
__global__ __launch_bounds__(256) void cast_pad(
    const float* __restrict__ src, __hip_bfloat16* __restrict__ dst,
    int sr, int sc, int dc) {
  const int r = blockIdx.x;
  for (int c = threadIdx.x; c < dc; c += 256) {
    float v = (r < sr && c < sc) ? src[(size_t)r * sc + c] : 0.f;
    dst[(size_t)r * dc + c] = __float2bfloat16(v);
  }
}

// ---------------------------------------------------------------------------
// bf16 GEMM-NT via MFMA 16x16x32: C = A @ B^T (+bias)(+silu)
// A: (M,K) bf16 row-major lda.  B: (N,K) bf16 row-major ldb (torch weights).
// Requires: K % 64 == 0, N % 64 == 0 (caller pads buffers); M bounds-checked.
// EPI: 0 = bf16 out; 1 = +bias +silu, bf16 out; 2 = +bias(n<D), f32 out.
// Tile 128x64x64, 256 threads = 4 waves in 2x2; wave does 64x32 (4x2 tiles).
// LDS XOR-swizzle on 16B granules: granule g of row r stored at g^(r&7).
// ---------------------------------------------------------------------------
template <int EPI>
__global__ __launch_bounds__(256) void gemm_bf16(
    const unsigned short* __restrict__ A, const unsigned short* __restrict__ B,
    const float* __restrict__ bias, void* __restrict__ Cout,
    int M, int Nn, int K, int lda, int ldb, int ldc) {
  constexpr int BM = 128, BN = 64, BK = 64;
  __shared__ unsigned short As[BM * BK];  // 16 KB
  __shared__ unsigned short Bs[BN * BK];  // 8 KB
  const int tid = threadIdx.x;
  const int wave = tid >> 6;
  const int lane = tid & 63;
  const int wm = wave >> 1;       // 0..1 -> m offset wm*64
  const int wn = wave & 1;        // 0..1 -> n offset wn*32
  const int ml = lane & 15;
  const int q = lane >> 4;        // quad 0..3
  const int m0 = blockIdx.y * BM;
  const int n0 = blockIdx.x * BN;

  f32x4_t acc[4][2];
#pragma unroll
  for (int i = 0; i < 4; i++)
#pragma unroll
    for (int j = 0; j < 2; j++) acc[i][j] = (f32x4_t)0.f;

  for (int k0 = 0; k0 < K; k0 += BK) {
    // stage A: 1024 granules of 8 bf16 (16 B)
#pragma unroll
    for (int i = 0; i < 4; i++) {
      int gid = tid + i * 256;
      int r = gid >> 3, g = gid & 7;
      int gr = m0 + r;
      uint4 v = make_uint4(0u, 0u, 0u, 0u);
      if (gr < M) v = *(const uint4*)(A + (size_t)gr * lda + k0 + g * 8);
      *(uint4*)(As + r * 64 + ((g ^ (r & 7)) * 8)) = v;
    }
    // stage B: 512 granules (N padded -> always in-bounds)
#pragma unroll
    for (int i = 0; i < 2; i++) {
      int gid = tid + i * 256;
      int r = gid >> 3, g = gid & 7;
      uint4 v = *(const uint4*)(B + (size_t)(n0 + r) * ldb + k0 + g * 8);
      *(uint4*)(Bs + r * 64 + ((g ^ (r & 7)) * 8)) = v;
    }
    __syncthreads();
#pragma unroll
    for (int kk = 0; kk < 2; kk++) {  // two K=32 steps per stage
      bf16x8_t a[4], b[2];
#pragma unroll
      for (int im = 0; im < 4; im++) {
        int row = wm * 64 + im * 16 + ml;
        int g = kk * 4 + q;
        a[im] = *(const bf16x8_t*)(As + row * 64 + ((g ^ (row & 7)) * 8));
      }
#pragma unroll
      for (int jn = 0; jn < 2; jn++) {
        int row = wn * 32 + jn * 16 + ml;
        int g = kk * 4 + q;
        b[jn] = *(const bf16x8_t*)(Bs + row * 64 + ((g ^ (row & 7)) * 8));
      }
#pragma unroll
      for (int im = 0; im < 4; im++)
#pragma unroll
        for (int jn = 0; jn < 2; jn++)
          acc[im][jn] = __builtin_amdgcn_mfma_f32_16x16x32_bf16(
              a[im], b[jn], acc[im][jn], 0, 0, 0);
    }
    __syncthreads();
  }

  // epilogue: D[m][n], n = lane&15, m = quad*4 + reg  [verified m89/m91]
#pragma unroll
  for (int im = 0; im < 4; im++) {
#pragma unroll
    for (int jn = 0; jn < 2; jn++) {
      int gn = n0 + wn * 32 + jn * 16 + ml;
#pragma unroll
      for (int reg = 0; reg < 4; reg++) {
        int gm = m0 + wm * 64 + im * 16 + q * 4 + reg;
        if (gm >= M) continue;
        float v = acc[im][jn][reg];
        if (EPI == 1) {
          v += bias[gn];
          v = v / (1.f + __expf(-v));  // silu
          ((__hip_bfloat16*)Cout)[(size_t)gm * ldc + gn] = __float2bfloat16(v);
        } else if (EPI == 2) {
          v += (gn < D) ? bias[gn] : 0.f;
          ((float*)Cout)[(size_t)gm * ldc + gn] = v;
        } else {
          ((__hip_bfloat16*)Cout)[(size_t)gm * ldc + gn] = __float2bfloat16(v);
        }
      }
    }
  }
}

// ---------------------------------------------------------------------------
// Edge CSR-by-target build (runs every launch; ws is re-poisoned)
// ---------------------------------------------------------------------------
__global__ __launch_bounds__(256) void zero_deg(int* __restrict__ deg) {
  int i = blockIdx.x * 256 + threadIdx.x;
  if (i < N_NODES) deg[i] = 0;
}

__global__ __launch_bounds__(256) void hist_tgt(
    const int* __restrict__ ei, int* __restrict__ deg) {
  int e = blockIdx.x * 256 + threadIdx.x;
  if (e < N_EDGES) atomicAdd(&deg[ei[N_EDGES + e]], 1);
}

// single block: exclusive scan over 10000 bins -> rs[0..N], woff copy
__global__ __launch_bounds__(256) void scan_deg(
    const int* __restrict__ deg, int* __restrict__ rs, int* __restrict__ woff) {
  __shared__ int part[256];
  const int t = threadIdx.x;
  const int base = t * 40;  // 256*40 = 10240 >= 10000
  int sum = 0;
  for (int i = 0; i < 40; i++) {
    int idx = base + i;
    if (idx < N_NODES) sum += deg[idx];
  }
  part[t] = sum;
  __syncthreads();
  if (t == 0) {
    int run = 0;
    for (int i = 0; i < 256; i++) { int tmp = part[i]; part[i] = run; run += tmp; }
    rs[N_NODES] = run;  // == N_EDGES
  }
  __syncthreads();
  int run = part[t];
  for (int i = 0; i < 40; i++) {
    int idx = base + i;
    if (idx < N_NODES) {
      rs[idx] = run;
      woff[idx] = run;
      run += deg[idx];
    }
  }
}

__global__ __launch_bounds__(256) void place_edges(
    const int* __restrict__ ei, int* __restrict__ woff, int* __restrict__ esrc) {
  int e = blockIdx.x * 256 + threadIdx.x;
  if (e < N_EDGES) {
    int pos = atomicAdd(&woff[ei[N_EDGES + e]], 1);
    esrc[pos] = ei[e];
  }
}

// ---------------------------------------------------------------------------
// CSR of structure-constant triples sorted by output index K (as round 2)
// ---------------------------------------------------------------------------
__global__ __launch_bounds__(256) void build_csrK(
    const int* __restrict__ Iv, const int* __restrict__ Jv,
    const int* __restrict__ Kv, const float* __restrict__ Cv,
    int* __restrict__ row_start, int* __restrict__ tI,
    int* __restrict__ tJ, float* __restrict__ tC) {
  __shared__ int cnt[D];
  __shared__ int off[D];
  const int tid = threadIdx.x;
  for (int k = tid; k < D; k += 256) cnt[k] = 0;
  __syncthreads();
  for (int t = tid; t < NNZ; t += 256) atomicAdd(&cnt[Kv[t]], 1);
  __syncthreads();
  if (tid == 0) {
    int run = 0;
    for (int k = 0; k < D; k++) { off[k] = run; row_start[k] = run; run += cnt[k]; }
    row_start[D] = run;
  }
  __syncthreads();
  for (int t = tid; t < NNZ; t += 256) {
    int pos = atomicAdd(&off[Kv[t]], 1);
    tI[pos] = Iv[t];
    tJ[pos] = Jv[t];
    tC[pos] = Cv[t];
  }
}

// ---------------------------------------------------------------------------
// Fused gather + bracket, block per node, zero atomics:
//   S[n] = sum_{e: tgt=n} P[src(e)]          (4 waves x 4 edges in flight)
//   agg[n][k] = sum_{t in CSRK row k} C_t * S[n][I_t] * F[n][J_t]
// P is bf16 (DP-stride); agg written bf16 (DP-stride, cols D..DP-1 zeroed).
// ---------------------------------------------------------------------------
__global__ __launch_bounds__(256) void gather_bracket(
    const unsigned short* __restrict__ P, const float* __restrict__ F,
    const int* __restrict__ rs, const int* __restrict__ esrc,
    const int* __restrict__ row_start, const int* __restrict__ tI,
    const int* __restrict__ tJ, const float* __restrict__ tC,
    __hip_bfloat16* __restrict__ agg) {
  const int n = blockIdx.x;
  __shared__ float sF[D];
  __shared__ float sPart[4][DP];
  __shared__ float sS[DP];
  const int tid = threadIdx.x;
  const int wave = tid >> 6;
  const int lane = tid & 63;

  if (tid < D) sF[tid] = F[(size_t)n * D + tid];

  float a0 = 0.f, a1 = 0.f, a2 = 0.f, a3 = 0.f;
  const int beg = rs[n], end = rs[n + 1];
  if (lane < 62) {
    for (int i = beg + wave; i < end; i += 4) {
      const int src = esrc[i];
      ushort4 u = ((const ushort4*)(P + (size_t)src * DP))[lane];
      a0 += bf2f(u.x); a1 += bf2f(u.y); a2 += bf2f(u.z); a3 += bf2f(u.w);
    }
    sPart[wave][lane * 4 + 0] = a0;
    sPart[wave][lane * 4 + 1] = a1;
    sPart[wave][lane * 4 + 2] = a2;
    sPart[wave][lane * 4 + 3] = a3;
  }
  __syncthreads();
  if (tid < D) sS[tid] = sPart[0][tid] + sPart[1][tid] + sPart[2][tid] + sPart[3][tid];
  __syncthreads();

  if (tid < D) {
    float acc = 0.f;
    const int b = row_start[tid], e = row_start[tid + 1];
    for (int t = b; t < e; t++) acc += tC[t] * sS[tI[t]] * sF[tJ[t]];
    agg[(size_t)n * DP + tid] = __float2bfloat16(acc);
  } else {
    agg[(size_t)n * DP + tid] = __float2bfloat16(0.f);  // K-pad for GEMM2
  }
}

// ---------------------------------------------------------------------------
// Residual + LayerNorm (h2 has DP stride)
// ---------------------------------------------------------------------------
__global__ __launch_bounds__(256) void ln_kernel(
    const float* __restrict__ x0, const float* __restrict__ h2,
    const float* __restrict__ gamma, const float* __restrict__ beta,
    float* __restrict__ out) {
  const int n = blockIdx.x;
  const int tid = threadIdx.x;
  __shared__ float red[256];
  float x = 0.f;
  if (tid < D) x = x0[(size_t)n * D + tid] + h2[(size_t)n * DP + tid];
  red[tid] = (tid < D) ? x : 0.f;
  __syncthreads();
  for (int s = 128; s > 0; s >>= 1) {
    if (tid < s) red[tid] += red[tid + s];
    __syncthreads();
  }
  const float mu = red[0] / (float)D;
  __syncthreads();
  const float xc = (tid < D) ? (x - mu) : 0.f;
  red[tid] = xc * xc;
  __syncthreads();
  for (int s = 128; s > 0; s >>= 1) {
    if (tid < s) red[tid] += red[tid + s];
    __syncthreads();
  }
  const float var = red[0] / (float)D;
  const float rstd = rsqrtf(var + LN_EPS);
  if (tid < D) out[(size_t)n * D + tid] = xc * rstd * gamma[tid] + beta[tid];
}

// ---------------------------------------------------------------------------
extern "C" void kernel_launch(void* const* d_in, const int* in_sizes, int n_in,
                              void* d_out, int out_size, void* d_ws, size_t ws_size,
                              hipStream_t stream) {
  const float* features = (const float*)d_in[0];
  const int*   ei       = (const int*)d_in[1];   // (2, E)
  const float* W_msg    = (const float*)d_in[2]; // (D, D)
  const float* W1       = (const float*)d_in[3]; // (H, D)
  const float* b1       = (const float*)d_in[4];
  const float* W2       = (const float*)d_in[5]; // (D, H)
  const float* b2       = (const float*)d_in[6];
  const float* gamma    = (const float*)d_in[7];
  const float* beta     = (const float*)d_in[8];
  const int*   Iv       = (const int*)d_in[9];
  const int*   Jv       = (const int*)d_in[10];
  const int*   Kv       = (const int*)d_in[11];
  const float* Cv       = (const float*)d_in[12];
  float* out = (float*)d_out;

  // workspace carve-up (256 B aligned)
  char* cur = (char*)d_ws;
  auto alloc = [&](size_t bytes) {
    char* p = cur;
    cur += (bytes + 255) & ~(size_t)255;
    return p;
  };
  unsigned short* featB = (unsigned short*)alloc((size_t)N_NODES * DP * 2); // 5.12 MB
  unsigned short* WmB   = (unsigned short*)alloc((size_t)DP * DP * 2);
  unsigned short* W1B   = (unsigned short*)alloc((size_t)HDIM * DP * 2);
  unsigned short* W2B   = (unsigned short*)alloc((size_t)DP * HDIM * 2);
  unsigned short* P     = (unsigned short*)alloc((size_t)N_NODES * DP * 2); // 5.12 MB
  __hip_bfloat16* aggB  = (__hip_bfloat16*)alloc((size_t)N_NODES * DP * 2); // 5.12 MB
  unsigned short* H1B   = (unsigned short*)alloc((size_t)N_NODES * HDIM * 2); // 10.24 MB
  float*          H2    = (float*)alloc((size_t)N_NODES * DP * 4);          // 10.24 MB
  int* rsK  = (int*)alloc((D + 1) * 4);
  int* tI   = (int*)alloc(NNZ * 4);
  int* tJ   = (int*)alloc(NNZ * 4);
  float* tC = (float*)alloc(NNZ * 4);
  int* deg  = (int*)alloc(N_NODES * 4);
  int* rs   = (int*)alloc((N_NODES + 1) * 4);
  int* woff = (int*)alloc(N_NODES * 4);
  int* esrc = (int*)alloc(N_EDGES * 4);

  dim3 blk(256);

  // casts (bf16, padded)
  cast_pad<<<N_NODES, blk, 0, stream>>>(features, (__hip_bfloat16*)featB, N_NODES, D, DP);
  cast_pad<<<DP, blk, 0, stream>>>(W_msg, (__hip_bfloat16*)WmB, D, D, DP);
  cast_pad<<<HDIM, blk, 0, stream>>>(W1, (__hip_bfloat16*)W1B, HDIM, D, DP);
  cast_pad<<<DP, blk, 0, stream>>>(W2, (__hip_bfloat16*)W2B, D, HDIM, HDIM);

  // edge CSR by target
  zero_deg<<<(N_NODES + 255) / 256, blk, 0, stream>>>(deg);
  hist_tgt<<<(N_EDGES + 255) / 256, blk, 0, stream>>>(ei, deg);
  scan_deg<<<1, blk, 0, stream>>>(deg, rs, woff);
  place_edges<<<(N_EDGES + 255) / 256, blk, 0, stream>>>(ei, woff, esrc);

  // triple CSR by K
  build_csrK<<<1, blk, 0, stream>>>(Iv, Jv, Kv, Cv, rsK, tI, tJ, tC);

  // 1) P = feat @ Wm^T  (bf16 MFMA, bf16 out)
  gemm_bf16<0><<<dim3(DP / 64, (N_NODES + 127) / 128), blk, 0, stream>>>(
      featB, WmB, nullptr, P, N_NODES, DP, DP, DP, DP, DP);
  // 2) fused gather + bracket -> aggB (bf16)
  gather_bracket<<<N_NODES, blk, 0, stream>>>(P, features, rs, esrc, rsK, tI, tJ, tC, aggB);
  // 3) H1 = silu(agg @ W1^T + b1)  (bf16 out)
  gemm_bf16<1><<<dim3(HDIM / 64, (N_NODES + 127) / 128), blk, 0, stream>>>(
      (const unsigned short*)aggB, W1B, b1, H1B, N_NODES, HDIM, DP, DP, DP, HDIM);
  // 4) H2 = H1 @ W2^T + b2  (f32 out)
  gemm_bf16<2><<<dim3(DP / 64, (N_NODES + 127) / 128), blk, 0, stream>>>(
      H1B, W2B, b2, H2, N_NODES, DP, HDIM, HDIM, HDIM, DP);
  // 5) out = LN(features + H2)
  ln_kernel<<<N_NODES, blk, 0, stream>>>(features, H2, gamma, beta, out);
}

// Round 4
// 245.275 us; speedup vs baseline: 6.5282x; 1.2149x over previous
//
#include <hip/hip_runtime.h>
#include <hip/hip_bf16.h>

#define N_NODES 10000
#define N_EDGES 100000
#define D 248
#define DP 256      // padded D (K/N padding for MFMA tiles)
#define HDIM 512
#define NNZ 2480
#define LN_EPS 1e-5f

typedef __attribute__((ext_vector_type(8))) short bf16x8_t;  // 8 bf16 = 4 VGPRs
typedef __attribute__((ext_vector_type(4))) float f32x4_t;   // MFMA accum

__device__ __forceinline__ float bf2f(unsigned short u) {
  unsigned int x = ((unsigned int)u) << 16;
  return __builtin_bit_cast(float, x);
}

// ---------------------------------------------------------------------------
// Fused prep kernel, decoded by blockIdx.x:
//   [0, 10000)               cast features (N,D)f32 -> featB (N,DP)bf16
//   [10000, 10256)           cast W_msg (D,D)   -> WmB (DP,DP)
//   [10256, 10768)           cast W1 (H,D)      -> W1B (H,DP)
//   [10768, 11024)           cast W2 (D,H)      -> W2B (DP,H)
//   [11024, 11064)           deg[i] = 0
//   11064                    build CSR of triples by K (packed int2 {J<<16|I, C})
// ---------------------------------------------------------------------------
#define CAST_BLOCKS (N_NODES + DP + HDIM + DP)
#define ZERO_BLOCKS 40
#define PREP_BLOCKS (CAST_BLOCKS + ZERO_BLOCKS + 1)

__device__ __forceinline__ void cast_row(const float* src, __hip_bfloat16* dst,
                                         int r, int sr, int sc, int dc) {
  for (int c = threadIdx.x; c < dc; c += 256) {
    float v = (r < sr && c < sc) ? src[(size_t)r * sc + c] : 0.f;
    dst[(size_t)r * dc + c] = __float2bfloat16(v);
  }
}

__global__ __launch_bounds__(256) void prep_kernel(
    const float* __restrict__ features, const float* __restrict__ W_msg,
    const float* __restrict__ W1, const float* __restrict__ W2,
    __hip_bfloat16* __restrict__ featB, __hip_bfloat16* __restrict__ WmB,
    __hip_bfloat16* __restrict__ W1B, __hip_bfloat16* __restrict__ W2B,
    int* __restrict__ deg,
    const int* __restrict__ Iv, const int* __restrict__ Jv,
    const int* __restrict__ Kv, const float* __restrict__ Cv,
    int* __restrict__ rsK, int2* __restrict__ trip) {
  const int b = blockIdx.x;
  if (b < N_NODES) {
    cast_row(features, featB, b, N_NODES, D, DP);
  } else if (b < N_NODES + DP) {
    cast_row(W_msg, WmB, b - N_NODES, D, D, DP);
  } else if (b < N_NODES + DP + HDIM) {
    cast_row(W1, W1B, b - N_NODES - DP, HDIM, D, DP);
  } else if (b < CAST_BLOCKS) {
    cast_row(W2, W2B, b - N_NODES - DP - HDIM, D, HDIM, HDIM);
  } else if (b < CAST_BLOCKS + ZERO_BLOCKS) {
    int i = (b - CAST_BLOCKS) * 256 + threadIdx.x;
    if (i < N_NODES) deg[i] = 0;
  } else {
    // triple CSR by K, packed
    __shared__ int cnt[D];
    __shared__ int off[D];
    const int tid = threadIdx.x;
    for (int k = tid; k < D; k += 256) cnt[k] = 0;
    __syncthreads();
    for (int t = tid; t < NNZ; t += 256) atomicAdd(&cnt[Kv[t]], 1);
    __syncthreads();
    if (tid == 0) {
      int run = 0;
      for (int k = 0; k < D; k++) { off[k] = run; rsK[k] = run; run += cnt[k]; }
      rsK[D] = run;
    }
    __syncthreads();
    for (int t = tid; t < NNZ; t += 256) {
      int pos = atomicAdd(&off[Kv[t]], 1);
      trip[pos] = make_int2((Jv[t] << 16) | Iv[t], __float_as_int(Cv[t]));
    }
  }
}

// ---------------------------------------------------------------------------
// Edge CSR-by-target: histogram -> scan -> placement
// ---------------------------------------------------------------------------
__global__ __launch_bounds__(256) void hist_tgt(
    const int* __restrict__ ei, int* __restrict__ deg) {
  int e = blockIdx.x * 256 + threadIdx.x;
  if (e < N_EDGES) atomicAdd(&deg[ei[N_EDGES + e]], 1);
}

__global__ __launch_bounds__(256) void scan_deg(
    const int* __restrict__ deg, int* __restrict__ rs, int* __restrict__ woff) {
  __shared__ int part[256];
  const int t = threadIdx.x;
  const int base = t * 40;  // 256*40 = 10240 >= 10000
  int sum = 0;
  for (int i = 0; i < 40; i++) {
    int idx = base + i;
    if (idx < N_NODES) sum += deg[idx];
  }
  part[t] = sum;
  __syncthreads();
  if (t == 0) {
    int run = 0;
    for (int i = 0; i < 256; i++) { int tmp = part[i]; part[i] = run; run += tmp; }
    rs[N_NODES] = run;
  }
  __syncthreads();
  int run = part[t];
  for (int i = 0; i < 40; i++) {
    int idx = base + i;
    if (idx < N_NODES) { rs[idx] = run; woff[idx] = run; run += deg[idx]; }
  }
}

__global__ __launch_bounds__(256) void place_edges(
    const int* __restrict__ ei, int* __restrict__ woff, int* __restrict__ esrc) {
  int e = blockIdx.x * 256 + threadIdx.x;
  if (e < N_EDGES) {
    int pos = atomicAdd(&woff[ei[N_EDGES + e]], 1);
    esrc[pos] = ei[e];
  }
}

// ---------------------------------------------------------------------------
// bf16 GEMM-NT via MFMA 16x16x32: C = A @ B^T (+bias)(+silu)
// EPI: 0 = bf16 out; 1 = +bias +silu, bf16 out; 2 = +bias(n<D), f32 out.
// Tile 128x64x64, 4 waves 2x2, XOR-swizzled LDS.
// ---------------------------------------------------------------------------
template <int EPI>
__global__ __launch_bounds__(256) void gemm_bf16(
    const unsigned short* __restrict__ A, const unsigned short* __restrict__ B,
    const float* __restrict__ bias, void* __restrict__ Cout,
    int M, int Nn, int K, int lda, int ldb, int ldc) {
  constexpr int BM = 128;
  __shared__ unsigned short As[BM * 64];  // 16 KB
  __shared__ unsigned short Bs[64 * 64];  // 8 KB
  const int tid = threadIdx.x;
  const int wave = tid >> 6;
  const int lane = tid & 63;
  const int wm = wave >> 1;
  const int wn = wave & 1;
  const int ml = lane & 15;
  const int q = lane >> 4;
  const int m0 = blockIdx.y * BM;
  const int n0 = blockIdx.x * 64;

  f32x4_t acc[4][2];
#pragma unroll
  for (int i = 0; i < 4; i++)
#pragma unroll
    for (int j = 0; j < 2; j++) acc[i][j] = (f32x4_t)0.f;

  for (int k0 = 0; k0 < K; k0 += 64) {
#pragma unroll
    for (int i = 0; i < 4; i++) {
      int gid = tid + i * 256;
      int r = gid >> 3, g = gid & 7;
      int gr = m0 + r;
      uint4 v = make_uint4(0u, 0u, 0u, 0u);
      if (gr < M) v = *(const uint4*)(A + (size_t)gr * lda + k0 + g * 8);
      *(uint4*)(As + r * 64 + ((g ^ (r & 7)) * 8)) = v;
    }
#pragma unroll
    for (int i = 0; i < 2; i++) {
      int gid = tid + i * 256;
      int r = gid >> 3, g = gid & 7;
      uint4 v = *(const uint4*)(B + (size_t)(n0 + r) * ldb + k0 + g * 8);
      *(uint4*)(Bs + r * 64 + ((g ^ (r & 7)) * 8)) = v;
    }
    __syncthreads();
#pragma unroll
    for (int kk = 0; kk < 2; kk++) {
      bf16x8_t a[4], b[2];
#pragma unroll
      for (int im = 0; im < 4; im++) {
        int row = wm * 64 + im * 16 + ml;
        int g = kk * 4 + q;
        a[im] = *(const bf16x8_t*)(As + row * 64 + ((g ^ (row & 7)) * 8));
      }
#pragma unroll
      for (int jn = 0; jn < 2; jn++) {
        int row = wn * 32 + jn * 16 + ml;
        int g = kk * 4 + q;
        b[jn] = *(const bf16x8_t*)(Bs + row * 64 + ((g ^ (row & 7)) * 8));
      }
#pragma unroll
      for (int im = 0; im < 4; im++)
#pragma unroll
        for (int jn = 0; jn < 2; jn++)
          acc[im][jn] = __builtin_amdgcn_mfma_f32_16x16x32_bf16(
              a[im], b[jn], acc[im][jn], 0, 0, 0);
    }
    __syncthreads();
  }

  // D[m][n]: n = lane&15, m = quad*4 + reg  [verified m89/m91]
#pragma unroll
  for (int im = 0; im < 4; im++) {
#pragma unroll
    for (int jn = 0; jn < 2; jn++) {
      int gn = n0 + wn * 32 + jn * 16 + ml;
#pragma unroll
      for (int reg = 0; reg < 4; reg++) {
        int gm = m0 + wm * 64 + im * 16 + q * 4 + reg;
        if (gm >= M) continue;
        float v = acc[im][jn][reg];
        if (EPI == 1) {
          v += bias[gn];
          v = v / (1.f + __expf(-v));
          ((__hip_bfloat16*)Cout)[(size_t)gm * ldc + gn] = __float2bfloat16(v);
        } else if (EPI == 2) {
          v += (gn < D) ? bias[gn] : 0.f;
          ((float*)Cout)[(size_t)gm * ldc + gn] = v;
        } else {
          ((__hip_bfloat16*)Cout)[(size_t)gm * ldc + gn] = __float2bfloat16(v);
        }
      }
    }
  }
}

// ---------------------------------------------------------------------------
// Fused gather + bracket, ONE WAVE PER NODE (4 nodes/block), zero atomics.
//   S[n] = sum_{e: tgt=n} P[src(e)]   (edge ids shfl-broadcast, 4-unrolled)
//   agg[n][k] = sum_{t in rowK(k)} C_t * S[n][I_t] * F[n][J_t]
// ---------------------------------------------------------------------------
__global__ __launch_bounds__(256) void gather_bracket(
    const unsigned short* __restrict__ P, const float* __restrict__ F,
    const int* __restrict__ rs, const int* __restrict__ esrc,
    const int* __restrict__ rsK, const int2* __restrict__ trip,
    __hip_bfloat16* __restrict__ agg) {
  __shared__ float sS[4][DP];
  __shared__ float sF[4][DP];
  const int tid = threadIdx.x;
  const int wv = tid >> 6;
  const int lane = tid & 63;
  const int n = blockIdx.x * 4 + wv;  // grid = 2500, exact

  // F row -> LDS (62 float4 = 248 floats)
  if (lane < 62) ((float4*)sF[wv])[lane] = ((const float4*)(F + (size_t)n * D))[lane];

  // gather: edge ids coalesced once, broadcast by shfl; 4 accs for ILP
  const int beg = rs[n];
  const int deg = rs[n + 1] - beg;
  int eid = (lane < deg) ? esrc[beg + lane] : 0;
  float x0 = 0.f, y0 = 0.f, z0 = 0.f, w0 = 0.f;
  float x1 = 0.f, y1 = 0.f, z1 = 0.f, w1 = 0.f;
  const int degc = (deg < 64) ? deg : 64;
  const unsigned short* Pl = P + (size_t)lane * 4;
  int j = 0;
  for (; j + 4 <= degc; j += 4) {
    int s0 = __shfl(eid, j), s1 = __shfl(eid, j + 1);
    int s2 = __shfl(eid, j + 2), s3 = __shfl(eid, j + 3);
    if (lane < 62) {
      ushort4 u0 = *(const ushort4*)(Pl + (size_t)s0 * DP);
      ushort4 u1 = *(const ushort4*)(Pl + (size_t)s1 * DP);
      ushort4 u2 = *(const ushort4*)(Pl + (size_t)s2 * DP);
      ushort4 u3 = *(const ushort4*)(Pl + (size_t)s3 * DP);
      x0 += bf2f(u0.x) + bf2f(u1.x); y0 += bf2f(u0.y) + bf2f(u1.y);
      z0 += bf2f(u0.z) + bf2f(u1.z); w0 += bf2f(u0.w) + bf2f(u1.w);
      x1 += bf2f(u2.x) + bf2f(u3.x); y1 += bf2f(u2.y) + bf2f(u3.y);
      z1 += bf2f(u2.z) + bf2f(u3.z); w1 += bf2f(u2.w) + bf2f(u3.w);
    }
  }
  for (; j < deg; j++) {
    int s = (j < 64) ? __shfl(eid, j) : esrc[beg + j];
    if (lane < 62) {
      ushort4 u = *(const ushort4*)(Pl + (size_t)s * DP);
      x0 += bf2f(u.x); y0 += bf2f(u.y); z0 += bf2f(u.z); w0 += bf2f(u.w);
    }
  }
  if (lane < 62)
    ((float4*)sS[wv])[lane] = make_float4(x0 + x1, y0 + y1, z0 + z1, w0 + w1);
  __syncthreads();

  // bracket: lane owns k = lane + kk*64; packed triples (one 8B load each)
  const float* S = sS[wv];
  const float* Fr = sF[wv];
#pragma unroll
  for (int kk = 0; kk < 4; kk++) {
    int k = lane + kk * 64;
    float a = 0.f;
    if (k < D) {
      const int b = rsK[k], e = rsK[k + 1];
      for (int t = b; t < e; t++) {
        int2 tr = trip[t];
        a += __int_as_float(tr.y) * S[tr.x & 0xFFFF] * Fr[tr.x >> 16];
      }
    }
    agg[(size_t)n * DP + k] = __float2bfloat16(a);  // k in [D,DP) -> 0 pad
  }
}

// ---------------------------------------------------------------------------
// Residual + LayerNorm (h2 has DP stride)
// ---------------------------------------------------------------------------
__global__ __launch_bounds__(256) void ln_kernel(
    const float* __restrict__ x0, const float* __restrict__ h2,
    const float* __restrict__ gamma, const float* __restrict__ beta,
    float* __restrict__ out) {
  const int n = blockIdx.x;
  const int tid = threadIdx.x;
  __shared__ float red[256];
  float x = 0.f;
  if (tid < D) x = x0[(size_t)n * D + tid] + h2[(size_t)n * DP + tid];
  red[tid] = (tid < D) ? x : 0.f;
  __syncthreads();
  for (int s = 128; s > 0; s >>= 1) {
    if (tid < s) red[tid] += red[tid + s];
    __syncthreads();
  }
  const float mu = red[0] / (float)D;
  __syncthreads();
  const float xc = (tid < D) ? (x - mu) : 0.f;
  red[tid] = xc * xc;
  __syncthreads();
  for (int s = 128; s > 0; s >>= 1) {
    if (tid < s) red[tid] += red[tid + s];
    __syncthreads();
  }
  const float var = red[0] / (float)D;
  const float rstd = rsqrtf(var + LN_EPS);
  if (tid < D) out[(size_t)n * D + tid] = xc * rstd * gamma[tid] + beta[tid];
}

// ---------------------------------------------------------------------------
extern "C" void kernel_launch(void* const* d_in, const int* in_sizes, int n_in,
                              void* d_out, int out_size, void* d_ws, size_t ws_size,
                              hipStream_t stream) {
  const float* features = (const float*)d_in[0];
  const int*   ei       = (const int*)d_in[1];
  const float* W_msg    = (const float*)d_in[2];
  const float* W1       = (const float*)d_in[3];
  const float* b1       = (const float*)d_in[4];
  const float* W2       = (const float*)d_in[5];
  const float* b2       = (const float*)d_in[6];
  const float* gamma    = (const float*)d_in[7];
  const float* beta     = (const float*)d_in[8];
  const int*   Iv       = (const int*)d_in[9];
  const int*   Jv       = (const int*)d_in[10];
  const int*   Kv       = (const int*)d_in[11];
  const float* Cv       = (const float*)d_in[12];
  float* out = (float*)d_out;

  char* cur = (char*)d_ws;
  auto alloc = [&](size_t bytes) {
    char* p = cur;
    cur += (bytes + 255) & ~(size_t)255;
    return p;
  };
  __hip_bfloat16* featB = (__hip_bfloat16*)alloc((size_t)N_NODES * DP * 2);
  __hip_bfloat16* WmB   = (__hip_bfloat16*)alloc((size_t)DP * DP * 2);
  __hip_bfloat16* W1B   = (__hip_bfloat16*)alloc((size_t)HDIM * DP * 2);
  __hip_bfloat16* W2B   = (__hip_bfloat16*)alloc((size_t)DP * HDIM * 2);
  unsigned short* P     = (unsigned short*)alloc((size_t)N_NODES * DP * 2);
  __hip_bfloat16* aggB  = (__hip_bfloat16*)alloc((size_t)N_NODES * DP * 2);
  unsigned short* H1B   = (unsigned short*)alloc((size_t)N_NODES * HDIM * 2);
  float*          H2    = (float*)alloc((size_t)N_NODES * DP * 4);
  int*  rsK  = (int*)alloc((D + 1) * 4);
  int2* trip = (int2*)alloc(NNZ * 8);
  int*  deg  = (int*)alloc(N_NODES * 4);
  int*  rs   = (int*)alloc((N_NODES + 1) * 4);
  int*  woff = (int*)alloc(N_NODES * 4);
  int*  esrc = (int*)alloc(N_EDGES * 4);

  dim3 blk(256);

  // 1) fused casts + deg-zero + triple CSR (one launch)
  prep_kernel<<<PREP_BLOCKS, blk, 0, stream>>>(
      features, W_msg, W1, W2, featB, WmB, W1B, W2B, deg,
      Iv, Jv, Kv, Cv, rsK, trip);
  // 2) edge CSR by target
  hist_tgt<<<(N_EDGES + 255) / 256, blk, 0, stream>>>(ei, deg);
  scan_deg<<<1, blk, 0, stream>>>(deg, rs, woff);
  place_edges<<<(N_EDGES + 255) / 256, blk, 0, stream>>>(ei, woff, esrc);
  // 3) P = feat @ Wm^T
  gemm_bf16<0><<<dim3(DP / 64, (N_NODES + 127) / 128), blk, 0, stream>>>(
      (const unsigned short*)featB, (const unsigned short*)WmB, nullptr, P,
      N_NODES, DP, DP, DP, DP, DP);
  // 4) fused gather + bracket (wave per node)
  gather_bracket<<<N_NODES / 4, blk, 0, stream>>>(P, features, rs, esrc, rsK, trip, aggB);
  // 5) H1 = silu(agg @ W1^T + b1)
  gemm_bf16<1><<<dim3(HDIM / 64, (N_NODES + 127) / 128), blk, 0, stream>>>(
      (const unsigned short*)aggB, (const unsigned short*)W1B, b1, H1B,
      N_NODES, HDIM, DP, DP, DP, HDIM);
  // 6) H2 = H1 @ W2^T + b2
  gemm_bf16<2><<<dim3(DP / 64, (N_NODES + 127) / 128), blk, 0, stream>>>(
      H1B, (const unsigned short*)W2B, b2, H2, N_NODES, DP, HDIM, HDIM, HDIM, DP);
  // 7) out = LN(features + H2)
  ln_kernel<<<N_NODES, blk, 0, stream>>>(features, H2, gamma, beta, out);
}